// Round 10
// baseline (774.151 us; speedup 1.0000x reference)
//
#include <hip/hip_runtime.h>
#include <hip/hip_bf16.h>

// ---------------------------------------------------------------------------
// DEQ layer, MI355X round 14.
//  - FX-interleaved history ring: slot = 2048 rows x 512 f32, per row
//    [F d0..3][X d0..3] alternating 16B chunks. Anderson reads ONE 32B
//    contiguous region per slot per lane (was 2 x 16B in 2 distant 2MB
//    streams): 12 streams -> 6, same bytes, bit-identical values.
//    gemm2 writes F via index remap; memset replaced by init zeroing X0.
//  - colsum folded into gram (mode C, 1344 blocks): -1 launch.
//  - 2-phase double-buffered GEMMs (R12 win), 21-launch pmv, gram 64x32
//    + float2 staging (R13, verified 769us): unchanged.
// ---------------------------------------------------------------------------

#define B_ROWS 2048
#define D_LAT  256
#define D_CTX  256
#define D_HID  1024
#define KCAT   512
#define SLOT   (B_ROWS * D_LAT)
#define S2     (B_ROWS * 512)   // one FX slot (F+X interleaved)
#define NRING  7

typedef __bf16 bf16x8 __attribute__((ext_vector_type(8)));
typedef float f32x4 __attribute__((ext_vector_type(4)));
typedef float f32x2 __attribute__((ext_vector_type(2)));
typedef unsigned short u16;

// ---------------- init: zc = [bf16(0)|bf16(ctx)], uA=1, vA=0, G=0, X0=0 ----
__global__ void init_kernel(const float* __restrict__ ctx,
                            __hip_bfloat16* __restrict__ zc,
                            float* __restrict__ vA, float* __restrict__ uA,
                            float* __restrict__ G1p, float* __restrict__ G2,
                            float* __restrict__ FXh) {
  int i = blockIdx.x * 256 + threadIdx.x;
  if (i < B_ROWS * KCAT) {
    int b = i >> 9, c = i & 511;
    float v = (c < 256) ? 0.0f : ctx[b * 256 + (c - 256)];
    zc[i] = __float2bfloat16(v);
  }
  if (i < SLOT) {  // X part of slot 0 = 0
    int b = i >> 8, d = i & 255;
    FXh[(size_t)b * 512 + ((d & ~3) << 1) + 4 + (d & 3)] = 0.0f;
  }
  if (i < 512 * 512) G1p[i] = 0.0f;
  if (i < 256 * 256) G2[i] = 0.0f;
  if (i < KCAT) vA[i] = 0.0f;
  if (i < D_LAT) uA[i] = 1.0f;
}

// ---------------- Gram build + colsum, split-K x8, 64x32 tiles -------------
// blocks 0..1023:   G1' = W1^T W1 (mode A)
// blocks 1024..1279: G2 = W2 W2^T (mode B)
// blocks 1280..1343: colsum partials vA += W1^T ones (mode C)
__global__ __launch_bounds__(256) void gram_kernel(
    const float* __restrict__ W1, const float* __restrict__ W2,
    float* __restrict__ G1p, float* __restrict__ G2,
    float* __restrict__ vA) {
  __shared__ float As[32][66];
  __shared__ float Bs[32][34];
  const int tid = threadIdx.x;
  const int tx = tid & 15, ty = tid >> 4;

  int b = blockIdx.x;
  if (b >= 1280) {  // mode C
    int cb = b - 1280;
    for (int c = tid; c < KCAT; c += 256) {
      float s = 0.f;
#pragma unroll
      for (int r = 0; r < 16; r++) s += W1[(size_t)(16 * cb + r) * KCAT + c];
      atomicAdd(&vA[c], s);
    }
    return;
  }

  const float* X; float* G; int N, ti, tj, k0base; bool modeA;
  if (b < 1024) {
    modeA = true; X = W1; G = G1p; N = 512;
    int s = b >> 7, t = b & 127;
    ti = t >> 4; tj = t & 15; k0base = s * 128;
  } else {
    modeA = false; b -= 1024; X = W2; G = G2; N = 256;
    int s = b >> 5, t = b & 31;
    ti = t >> 3; tj = t & 7; k0base = s * 128;
  }

  float acc[4][2] = {};
  for (int k0 = k0base; k0 < k0base + 128; k0 += 32) {
    if (modeA) {
      for (int idx = tid; idx < 1024; idx += 256) {
        int r2 = (idx & 31) * 2, c = idx >> 5;
        f32x2 v = *(const f32x2*)(X + (size_t)(k0 + c) * 512 + ti * 64 + r2);
        *(f32x2*)&As[c][r2] = v;
      }
      for (int idx = tid; idx < 512; idx += 256) {
        int r2 = (idx & 15) * 2, c = idx >> 4;
        f32x2 v = *(const f32x2*)(X + (size_t)(k0 + c) * 512 + tj * 32 + r2);
        *(f32x2*)&Bs[c][r2] = v;
      }
    } else {
      for (int idx = tid; idx < 1024; idx += 256) {
        int c2 = (idx & 15) * 2, r = idx >> 4;
        f32x2 v = *(const f32x2*)(X + (size_t)(ti * 64 + r) * 1024 + k0 + c2);
        As[c2][r] = v[0];
        As[c2 + 1][r] = v[1];
      }
      for (int idx = tid; idx < 512; idx += 256) {
        int c2 = (idx & 15) * 2, r = idx >> 4;
        f32x2 v = *(const f32x2*)(X + (size_t)(tj * 32 + r) * 1024 + k0 + c2);
        Bs[c2][r] = v[0];
        Bs[c2 + 1][r] = v[1];
      }
    }
    __syncthreads();
#pragma unroll
    for (int kk = 0; kk < 32; kk++) {
      const float2* ap = (const float2*)&As[kk][ty * 4];
      float2 a0 = ap[0], a1 = ap[1];
      float2 b0 = *(const float2*)&Bs[kk][tx * 2];
      float a[4] = {a0.x, a0.y, a1.x, a1.y};
      float bb[2] = {b0.x, b0.y};
#pragma unroll
      for (int i = 0; i < 4; i++)
#pragma unroll
        for (int j = 0; j < 2; j++) acc[i][j] += a[i] * bb[j];
    }
    __syncthreads();
  }
#pragma unroll
  for (int i = 0; i < 4; i++)
#pragma unroll
    for (int j = 0; j < 2; j++)
      atomicAdd(&G[(size_t)(ti * 64 + ty * 4 + i) * N + tj * 32 + tx * 2 + j],
                acc[i][j]);
}

// ---------------- joint power matvec: out = 0.25 * G in --------------------
__global__ __launch_bounds__(256) void pmv_kernel(
    const float* __restrict__ G1p, const float* __restrict__ G2,
    const float* __restrict__ vi, float* __restrict__ vo,
    const float* __restrict__ ui, float* __restrict__ uo, int g1_active) {
  int gw = blockIdx.x * 4 + (threadIdx.x >> 6);
  int lane = threadIdx.x & 63;
  const float* G; const float* in; float* out; int n, r;
  if (gw < 512) {
    if (!g1_active) return;
    G = G1p; in = vi; out = vo; n = 512; r = gw;
  } else {
    G = G2; in = ui; out = uo; n = 256; r = gw - 512;
  }
  const float4* Gr = (const float4*)(G + (size_t)r * n);
  const float4* uv = (const float4*)in;
  float acc = 0.f;
  for (int c = lane; c < (n >> 2); c += 64) {
    float4 g = Gr[c], u = uv[c];
    acc += g.x * u.x + g.y * u.y + g.z * u.z + g.w * u.w;
  }
  for (int off = 32; off; off >>= 1) acc += __shfl_down(acc, off, 64);
  if (lane == 0) out[r] = 0.25f * acc;
}

// ---------------- sigma ----------------------------------------------------
// vA=v^21, vB=v^20, uA=u^20, uB=u^21 (0.25 damping compensated exactly).
__global__ __launch_bounds__(256) void sigma_kernel(
    const float* __restrict__ vA, const float* __restrict__ vB,
    const float* __restrict__ uA, const float* __restrict__ uB,
    float* __restrict__ sig) {
  float s[4] = {0.f, 0.f, 0.f, 0.f};
  for (int i = threadIdx.x; i < KCAT; i += 256) {
    s[0] += vA[i] * vB[i];
    s[1] += vA[i] * vA[i];
  }
  for (int i = threadIdx.x; i < D_LAT; i += 256) {
    s[2] += uA[i] * uA[i];
    s[3] += uA[i] * uB[i];
  }
  __shared__ float red[4][4];
  int lane = threadIdx.x & 63, w = threadIdx.x >> 6;
  for (int k = 0; k < 4; k++) {
    float a = s[k];
    for (int off = 32; off; off >>= 1) a += __shfl_down(a, off, 64);
    if (lane == 0) red[k][w] = a;
  }
  __syncthreads();
  if (threadIdx.x == 0) {
    float d0 = red[0][0] + red[0][1] + red[0][2] + red[0][3];
    float d1 = red[1][0] + red[1][1] + red[1][2] + red[1][3];
    float d2 = red[2][0] + red[2][1] + red[2][2] + red[2][3];
    float d3 = red[3][0] + red[3][1] + red[3][2] + red[3][3];
    sig[0] = sqrtf(0.25f * d0 / d1);
    sig[1] = sqrtf(0.25f * d2 / d3);
  }
}

// ---------------- fold sigma into bf16 weights -----------------------------
__global__ void wfold_kernel(const float* __restrict__ W1,
                             const float* __restrict__ W2,
                             const float* __restrict__ sig,
                             __hip_bfloat16* __restrict__ W1b,
                             __hip_bfloat16* __restrict__ W2b) {
  int i = blockIdx.x * 256 + threadIdx.x;
  if (i < D_HID * KCAT) W1b[i] = __float2bfloat16(W1[i] * sig[0]);
  int j = i - D_HID * KCAT;
  if (j >= 0 && j < D_LAT * D_HID) W2b[j] = __float2bfloat16(W2[j] * sig[1]);
}

// ---------------- warm-up fusions (FX layout) ------------------------------
// warm1: X1 = F0; zc left = bf16(F0)
__global__ void warm1_kernel(float* __restrict__ FXh,
                             __hip_bfloat16* __restrict__ zc) {
  int i = blockIdx.x * 256 + threadIdx.x;
  int b = i >> 8, d = i & 255;
  size_t off = (size_t)b * 512 + ((d & ~3) << 1) + (d & 3);
  float v = FXh[off];                    // F0
  FXh[S2 + off + 4] = v;                 // X1
  zc[b * KCAT + d] = __float2bfloat16(v);
}
// warm2: X2 = F0; F2 = F1
__global__ void warm2_kernel(float* __restrict__ FXh) {
  int i = blockIdx.x * 256 + threadIdx.x;
  int b = i >> 8, d = i & 255;
  size_t off = (size_t)b * 512 + ((d & ~3) << 1) + (d & 3);
  float f0 = FXh[off];
  float f1 = FXh[S2 + off];
  FXh[2 * S2 + off + 4] = f0;            // X2
  FXh[2 * S2 + off] = f1;                // F2
}

// ---------------- bf16 MFMA GEMM, 2-phase double-buffered LDS --------------
// OUT_MODE 0: bf16 -> Cb[m*N+n].  OUT_MODE 1: f32 -> FX F-part
// (Cf[m*512 + ((n&~3)<<1) + (n&3)]).
template <int BM, int BN, int K, int OUT_MODE>
__global__ __launch_bounds__(256) void gemm_mfma(
    const __hip_bfloat16* __restrict__ A, const __hip_bfloat16* __restrict__ W,
    const float* __restrict__ bias, float* __restrict__ Cf,
    __hip_bfloat16* __restrict__ Cb, int N) {
  __shared__ __align__(16) u16 lds[2][(BM + BN) * 64];
  const int tid = threadIdx.x;
  const int lane = tid & 63;
  const int wid = tid >> 6;
  const int wy = wid >> 1, wx = wid & 1;
  constexpr int WM = BM / 2, WN = BN / 2;
  constexpr int MB = WM / 16, NB = WN / 16;
  constexpr int NK = K / 64;
  const int bm = blockIdx.x * BM;
  const int bn = blockIdx.y * BN;
  const int rlo = lane & 15, quad = lane >> 4;

  f32x4 acc[MB][NB] = {};

  auto stage = [&](u16* base, int k0) {
    u16* As = base;
    u16* Ws = base + BM * 64;
    for (int c = tid; c < BM * 8; c += 256) {
      int r = c >> 3, o = (c & 7) ^ (r & 7);
      __builtin_amdgcn_global_load_lds(
          (const __attribute__((address_space(1))) void*)(A + (size_t)(bm + r) * K + k0 + o * 8),
          (__attribute__((address_space(3))) void*)(As + c * 8), 16, 0, 0);
    }
    for (int c = tid; c < BN * 8; c += 256) {
      int r = c >> 3, o = (c & 7) ^ (r & 7);
      __builtin_amdgcn_global_load_lds(
          (const __attribute__((address_space(1))) void*)(W + (size_t)(bn + r) * K + k0 + o * 8),
          (__attribute__((address_space(3))) void*)(Ws + c * 8), 16, 0, 0);
    }
  };
  auto compute = [&](const u16* base) {
    const u16* As = base;
    const u16* Ws = base + BM * 64;
#pragma unroll
    for (int kk = 0; kk < 2; kk++) {
      bf16x8 af[MB], bfr[NB];
#pragma unroll
      for (int mb = 0; mb < MB; mb++) {
        int r = wy * WM + mb * 16 + rlo;
        int o = (kk * 4 + quad) ^ (r & 7);
        af[mb] = *(const bf16x8*)(As + (r * 8 + o) * 8);
      }
#pragma unroll
      for (int nb = 0; nb < NB; nb++) {
        int r = wx * WN + nb * 16 + rlo;
        int o = (kk * 4 + quad) ^ (r & 7);
        bfr[nb] = *(const bf16x8*)(Ws + (r * 8 + o) * 8);
      }
#pragma unroll
      for (int mb = 0; mb < MB; mb++)
#pragma unroll
        for (int nb = 0; nb < NB; nb++)
          acc[mb][nb] = __builtin_amdgcn_mfma_f32_16x16x32_bf16(
              af[mb], bfr[nb], acc[mb][nb], 0, 0, 0);
    }
  };

  stage(&lds[0][0], 0);
  __syncthreads();
#pragma unroll 2
  for (int step = 0; step < NK; step++) {
    u16* cur = (step & 1) ? &lds[1][0] : &lds[0][0];
    u16* nxt = (step & 1) ? &lds[0][0] : &lds[1][0];
    if (step + 1 < NK) stage(nxt, (step + 1) * 64);
    compute(cur);
    if (step + 1 < NK) __syncthreads();
  }

#pragma unroll
  for (int mb = 0; mb < MB; mb++) {
#pragma unroll
    for (int nb = 0; nb < NB; nb++) {
      int n = bn + wx * WN + nb * 16 + rlo;
      float bv = bias[n];
#pragma unroll
      for (int rg = 0; rg < 4; rg++) {
        int m = bm + wy * WM + mb * 16 + quad * 4 + rg;
        float val = tanhf(acc[mb][nb][rg] + bv);
        if constexpr (OUT_MODE == 0) {
          Cb[(size_t)m * N + n] = __float2bfloat16(val);
        } else {
          Cf[(size_t)m * 512 + ((n & ~3) << 1) + (n & 3)] = val;
        }
      }
    }
  }
}

// ---------------- Anderson step v2.2 (wave/row, FX-interleaved ring) -------
// Lane owns elems [4l,4l+4): per slot ONE 32B contiguous region
// ([F 16B][X 16B]). 6 streams instead of 12, values bit-identical.
template <int MK, bool LAST>
__global__ __launch_bounds__(256) void anderson_step_kernel(
    float* __restrict__ FXh, float* __restrict__ out,
    __hip_bfloat16* __restrict__ zc, int t) {
  const int lane = threadIdx.x & 63;
  const int wid = threadIdx.x >> 6;
  const int b = blockIdx.x * 4 + wid;
  const size_t rowoff = (size_t)b * 512 + 8 * lane;

  f32x4 f[MK + 1], x[MK + 1];
#pragma unroll
  for (int i = 0; i <= MK; i++) {
    int sl = (t - 1 - i) % NRING;
    const float* p = FXh + (size_t)sl * S2 + rowoff;
    f[i] = *(const f32x4*)p;
    x[i] = *(const f32x4*)(p + 4);
  }

  const f32x4 r = f[0] - x[0];
  f32x4 dF[MK], dG[MK];
#pragma unroll
  for (int i = 0; i < MK; i++) {
    dF[i] = f[i] - f[i + 1];
    dG[i] = dF[i] - (x[i] - x[i + 1]);
  }

  constexpr int NV = MK * (MK + 1) / 2 + MK;
  float vals[NV];
  {
    int p = 0;
#pragma unroll
    for (int i = 0; i < MK; i++)
#pragma unroll
      for (int j = i; j < MK; j++) {
        f32x4 q = dG[i] * dG[j];
        vals[p++] = q[0] + q[1] + q[2] + q[3];
      }
#pragma unroll
    for (int i = 0; i < MK; i++) {
      f32x4 q = dG[i] * r;
      vals[p++] = q[0] + q[1] + q[2] + q[3];
    }
  }
#pragma unroll
  for (int off = 1; off <= 32; off <<= 1)
#pragma unroll
    for (int v = 0; v < NV; v++) vals[v] += __shfl_xor(vals[v], off, 64);

  float A[MK][MK], bv[MK], alpha[MK];
  {
    int p = 0;
#pragma unroll
    for (int i = 0; i < MK; i++)
#pragma unroll
      for (int j = i; j < MK; j++) {
        A[i][j] = vals[p];
        A[j][i] = vals[p];
        p++;
      }
#pragma unroll
    for (int i = 0; i < MK; i++) A[i][i] += 1e-4f;
#pragma unroll
    for (int i = 0; i < MK; i++) bv[i] = vals[p++];
  }

#pragma unroll
  for (int c = 0; c < MK; c++) {
    float inv = 1.0f / A[c][c];
#pragma unroll
    for (int rr = c + 1; rr < MK; rr++) {
      float fct = A[rr][c] * inv;
#pragma unroll
      for (int cc = c; cc < MK; cc++) A[rr][cc] -= fct * A[c][cc];
      bv[rr] -= fct * bv[c];
    }
  }
#pragma unroll
  for (int i = MK - 1; i >= 0; i--) {
    float s = bv[i];
#pragma unroll
    for (int j = i + 1; j < MK; j++) s -= A[i][j] * alpha[j];
    alpha[i] = s / A[i][i];
  }

  f32x4 xo = f[0];
#pragma unroll
  for (int i = 0; i < MK; i++) xo -= dF[i] * alpha[i];
  if constexpr (LAST) {
    *(f32x4*)(out + (size_t)b * D_LAT + 4 * lane) = xo;
  } else {
    *(f32x4*)(FXh + (size_t)(t % NRING) * S2 + rowoff + 4) = xo;
    union { __hip_bfloat16 h[4]; unsigned long long u; } cv;
#pragma unroll
    for (int j = 0; j < 4; j++) cv.h[j] = __float2bfloat16(xo[j]);
    *(unsigned long long*)(zc + (size_t)b * KCAT + 4 * lane) = cv.u;
  }
}

// ---------------- host orchestration ---------------------------------------
static void eval_f(const __hip_bfloat16* zc, const __hip_bfloat16* W1b,
                   const __hip_bfloat16* W2b, const float* b1, const float* b2,
                   __hip_bfloat16* hb, float* FXslot, hipStream_t stream) {
  gemm_mfma<64, 64, KCAT, 0><<<dim3(B_ROWS / 64, D_HID / 64), 256, 0,
                               stream>>>(zc, W1b, b1, nullptr, hb, D_HID);
  gemm_mfma<32, 32, D_HID, 1><<<dim3(B_ROWS / 32, D_LAT / 32), 256, 0,
                                stream>>>(hb, W2b, b2, FXslot, nullptr, D_LAT);
}

extern "C" void kernel_launch(void* const* d_in, const int* in_sizes, int n_in,
                              void* d_out, int out_size, void* d_ws,
                              size_t ws_size, hipStream_t stream) {
  const float* ctx = (const float*)d_in[0];
  const float* W1 = (const float*)d_in[1];
  const float* b1 = (const float*)d_in[2];
  const float* W2 = (const float*)d_in[3];
  const float* b2 = (const float*)d_in[4];
  float* out = (float*)d_out;

  float* ws = (float*)d_ws;
  float* sig = ws;                       // 16
  float* vA = ws + 16;                   // 512
  float* vB = vA + KCAT;                 // 512
  float* uA = vB + KCAT;                 // 256
  float* uB = uA + D_LAT;                // 256
  float* G1p = uB + D_LAT;               // 512*512
  float* G2 = G1p + KCAT * KCAT;         // 256*256
  float* FXh = G2 + D_LAT * D_LAT;       // 7 * S2 (28 MB)
  __hip_bfloat16* W1b = (__hip_bfloat16*)(FXh + NRING * S2);   // 524288
  __hip_bfloat16* W2b = W1b + D_HID * KCAT;                    // 262144
  __hip_bfloat16* zc = W2b + D_LAT * D_HID;                    // 2048*512
  __hip_bfloat16* hb = zc + B_ROWS * KCAT;                     // 2048*1024
  // ~38.5 MB total

  init_kernel<<<(B_ROWS * KCAT + 255) / 256, 256, 0, stream>>>(
      ctx, zc, vA, uA, G1p, G2, FXh);
  gram_kernel<<<1344, 256, 0, stream>>>(W1, W2, G1p, G2, vA);

  // damped power chain: u-side its 1..21 (u0=ones->u21); v-side its 2..21
  for (int it = 1; it <= 21; it++) {
    const float* vi; float* vo;
    const float* ui; float* uo;
    if (it & 1) { vi = vB; vo = vA; ui = uA; uo = uB; }
    else        { vi = vA; vo = vB; ui = uB; uo = uA; }
    pmv_kernel<<<192, 256, 0, stream>>>(G1p, G2, vi, vo, ui, uo, it >= 2);
  }
  // final: vA=v21, vB=v20, uA=u20, uB=u21
  sigma_kernel<<<1, 256, 0, stream>>>(vA, vB, uA, uB, sig);
  wfold_kernel<<<(D_HID * KCAT + D_LAT * D_HID + 255) / 256, 256, 0, stream>>>(
      W1, W2, sig, W1b, W2b);

  // F0 = f(x0) into FX slot 0 (X0 zeroed by init)
  eval_f(zc, W1b, W2b, b1, b2, hb, FXh, stream);
  // X1 = F0; zc = bf16(F0); F1 = f(X1)
  warm1_kernel<<<SLOT / 256, 256, 0, stream>>>(FXh, zc);
  eval_f(zc, W1b, W2b, b1, b2, hb, FXh + S2, stream);
  // X2 = F0; F2 = F1
  warm2_kernel<<<SLOT / 256, 256, 0, stream>>>(FXh);

  // Anderson loop: t = 3..25
  for (int t = 3; t <= 25; t++) {
    int mk = (t - 1 < 5) ? (t - 1) : 5;
    dim3 g(B_ROWS / 4);
    if (t == 25) {
      anderson_step_kernel<5, true><<<g, 256, 0, stream>>>(FXh, out, nullptr, t);
    } else {
      if (mk == 2)
        anderson_step_kernel<2, false><<<g, 256, 0, stream>>>(FXh, nullptr, zc, t);
      else if (mk == 3)
        anderson_step_kernel<3, false><<<g, 256, 0, stream>>>(FXh, nullptr, zc, t);
      else if (mk == 4)
        anderson_step_kernel<4, false><<<g, 256, 0, stream>>>(FXh, nullptr, zc, t);
      else
        anderson_step_kernel<5, false><<<g, 256, 0, stream>>>(FXh, nullptr, zc, t);
      eval_f(zc, W1b, W2b, b1, b2, hb, FXh + (size_t)(t % NRING) * S2, stream);
    }
  }
}

// Round 11
// 761.906 us; speedup vs baseline: 1.0161x; 1.0161x over previous
//
#include <hip/hip_runtime.h>
#include <hip/hip_bf16.h>

// ---------------------------------------------------------------------------
// DEQ layer, MI355X round 15.
//  - REVERT FX-interleave (R14 neutral-negative): back to separate Xh/Fh
//    ring (R13, verified 769us). Anderson declared structurally floored
//    (~14.7us): traffic irreducible, waves pinned at 2048, fusion blocked.
//  - Launch-count harvest: colsum -> gram mode-C; warm1+warm2+memset
//    eliminated via gemm2 epilogue modes (eval0 writes F0,X1,X2,zc;
//    eval1 writes F1,F2; init zeroes X0). Bit-identical stores, -4 nodes.
//  - 2-phase double-buffered GEMMs (R12), 21-launch pmv, gram 64x32 +
//    float2 staging (R13): unchanged.
// ---------------------------------------------------------------------------

#define B_ROWS 2048
#define D_LAT  256
#define D_CTX  256
#define D_HID  1024
#define KCAT   512
#define SLOT   (B_ROWS * D_LAT)
#define NRING  7

typedef __bf16 bf16x8 __attribute__((ext_vector_type(8)));
typedef float f32x4 __attribute__((ext_vector_type(4)));
typedef float f32x2 __attribute__((ext_vector_type(2)));
typedef unsigned short u16;

// ---------------- init: zc, uA=1, vA=0, G=0, X0=0 --------------------------
__global__ void init_kernel(const float* __restrict__ ctx,
                            __hip_bfloat16* __restrict__ zc,
                            float* __restrict__ vA, float* __restrict__ uA,
                            float* __restrict__ G1p, float* __restrict__ G2,
                            float* __restrict__ Xh) {
  int i = blockIdx.x * 256 + threadIdx.x;
  if (i < B_ROWS * KCAT) {
    int b = i >> 9, c = i & 511;
    float v = (c < 256) ? 0.0f : ctx[b * 256 + (c - 256)];
    zc[i] = __float2bfloat16(v);
  }
  if (i < SLOT) Xh[i] = 0.0f;  // X slot 0
  if (i < 512 * 512) G1p[i] = 0.0f;
  if (i < 256 * 256) G2[i] = 0.0f;
  if (i < KCAT) vA[i] = 0.0f;
  if (i < D_LAT) uA[i] = 1.0f;
}

// ---------------- Gram build + colsum, split-K x8, 64x32 tiles -------------
// blocks 0..1023:   G1' = W1^T W1 (mode A)
// blocks 1024..1279: G2 = W2 W2^T (mode B)
// blocks 1280..1343: colsum partials vA += W1^T ones (mode C)
__global__ __launch_bounds__(256) void gram_kernel(
    const float* __restrict__ W1, const float* __restrict__ W2,
    float* __restrict__ G1p, float* __restrict__ G2,
    float* __restrict__ vA) {
  __shared__ float As[32][66];
  __shared__ float Bs[32][34];
  const int tid = threadIdx.x;
  const int tx = tid & 15, ty = tid >> 4;

  int b = blockIdx.x;
  if (b >= 1280) {  // mode C
    int cb = b - 1280;
    for (int c = tid; c < KCAT; c += 256) {
      float s = 0.f;
#pragma unroll
      for (int r = 0; r < 16; r++) s += W1[(size_t)(16 * cb + r) * KCAT + c];
      atomicAdd(&vA[c], s);
    }
    return;
  }

  const float* X; float* G; int N, ti, tj, k0base; bool modeA;
  if (b < 1024) {
    modeA = true; X = W1; G = G1p; N = 512;
    int s = b >> 7, t = b & 127;
    ti = t >> 4; tj = t & 15; k0base = s * 128;
  } else {
    modeA = false; b -= 1024; X = W2; G = G2; N = 256;
    int s = b >> 5, t = b & 31;
    ti = t >> 3; tj = t & 7; k0base = s * 128;
  }

  float acc[4][2] = {};
  for (int k0 = k0base; k0 < k0base + 128; k0 += 32) {
    if (modeA) {
      for (int idx = tid; idx < 1024; idx += 256) {
        int r2 = (idx & 31) * 2, c = idx >> 5;
        f32x2 v = *(const f32x2*)(X + (size_t)(k0 + c) * 512 + ti * 64 + r2);
        *(f32x2*)&As[c][r2] = v;
      }
      for (int idx = tid; idx < 512; idx += 256) {
        int r2 = (idx & 15) * 2, c = idx >> 4;
        f32x2 v = *(const f32x2*)(X + (size_t)(k0 + c) * 512 + tj * 32 + r2);
        *(f32x2*)&Bs[c][r2] = v;
      }
    } else {
      for (int idx = tid; idx < 1024; idx += 256) {
        int c2 = (idx & 15) * 2, r = idx >> 4;
        f32x2 v = *(const f32x2*)(X + (size_t)(ti * 64 + r) * 1024 + k0 + c2);
        As[c2][r] = v[0];
        As[c2 + 1][r] = v[1];
      }
      for (int idx = tid; idx < 512; idx += 256) {
        int c2 = (idx & 15) * 2, r = idx >> 4;
        f32x2 v = *(const f32x2*)(X + (size_t)(tj * 32 + r) * 1024 + k0 + c2);
        Bs[c2][r] = v[0];
        Bs[c2 + 1][r] = v[1];
      }
    }
    __syncthreads();
#pragma unroll
    for (int kk = 0; kk < 32; kk++) {
      const float2* ap = (const float2*)&As[kk][ty * 4];
      float2 a0 = ap[0], a1 = ap[1];
      float2 b0 = *(const float2*)&Bs[kk][tx * 2];
      float a[4] = {a0.x, a0.y, a1.x, a1.y};
      float bb[2] = {b0.x, b0.y};
#pragma unroll
      for (int i = 0; i < 4; i++)
#pragma unroll
        for (int j = 0; j < 2; j++) acc[i][j] += a[i] * bb[j];
    }
    __syncthreads();
  }
#pragma unroll
  for (int i = 0; i < 4; i++)
#pragma unroll
    for (int j = 0; j < 2; j++)
      atomicAdd(&G[(size_t)(ti * 64 + ty * 4 + i) * N + tj * 32 + tx * 2 + j],
                acc[i][j]);
}

// ---------------- joint power matvec: out = 0.25 * G in --------------------
__global__ __launch_bounds__(256) void pmv_kernel(
    const float* __restrict__ G1p, const float* __restrict__ G2,
    const float* __restrict__ vi, float* __restrict__ vo,
    const float* __restrict__ ui, float* __restrict__ uo, int g1_active) {
  int gw = blockIdx.x * 4 + (threadIdx.x >> 6);
  int lane = threadIdx.x & 63;
  const float* G; const float* in; float* out; int n, r;
  if (gw < 512) {
    if (!g1_active) return;
    G = G1p; in = vi; out = vo; n = 512; r = gw;
  } else {
    G = G2; in = ui; out = uo; n = 256; r = gw - 512;
  }
  const float4* Gr = (const float4*)(G + (size_t)r * n);
  const float4* uv = (const float4*)in;
  float acc = 0.f;
  for (int c = lane; c < (n >> 2); c += 64) {
    float4 g = Gr[c], u = uv[c];
    acc += g.x * u.x + g.y * u.y + g.z * u.z + g.w * u.w;
  }
  for (int off = 32; off; off >>= 1) acc += __shfl_down(acc, off, 64);
  if (lane == 0) out[r] = 0.25f * acc;
}

// ---------------- sigma ----------------------------------------------------
// vA=v^21, vB=v^20, uA=u^20, uB=u^21 (0.25 damping compensated exactly).
__global__ __launch_bounds__(256) void sigma_kernel(
    const float* __restrict__ vA, const float* __restrict__ vB,
    const float* __restrict__ uA, const float* __restrict__ uB,
    float* __restrict__ sig) {
  float s[4] = {0.f, 0.f, 0.f, 0.f};
  for (int i = threadIdx.x; i < KCAT; i += 256) {
    s[0] += vA[i] * vB[i];
    s[1] += vA[i] * vA[i];
  }
  for (int i = threadIdx.x; i < D_LAT; i += 256) {
    s[2] += uA[i] * uA[i];
    s[3] += uA[i] * uB[i];
  }
  __shared__ float red[4][4];
  int lane = threadIdx.x & 63, w = threadIdx.x >> 6;
  for (int k = 0; k < 4; k++) {
    float a = s[k];
    for (int off = 32; off; off >>= 1) a += __shfl_down(a, off, 64);
    if (lane == 0) red[k][w] = a;
  }
  __syncthreads();
  if (threadIdx.x == 0) {
    float d0 = red[0][0] + red[0][1] + red[0][2] + red[0][3];
    float d1 = red[1][0] + red[1][1] + red[1][2] + red[1][3];
    float d2 = red[2][0] + red[2][1] + red[2][2] + red[2][3];
    float d3 = red[3][0] + red[3][1] + red[3][2] + red[3][3];
    sig[0] = sqrtf(0.25f * d0 / d1);
    sig[1] = sqrtf(0.25f * d2 / d3);
  }
}

// ---------------- fold sigma into bf16 weights -----------------------------
__global__ void wfold_kernel(const float* __restrict__ W1,
                             const float* __restrict__ W2,
                             const float* __restrict__ sig,
                             __hip_bfloat16* __restrict__ W1b,
                             __hip_bfloat16* __restrict__ W2b) {
  int i = blockIdx.x * 256 + threadIdx.x;
  if (i < D_HID * KCAT) W1b[i] = __float2bfloat16(W1[i] * sig[0]);
  int j = i - D_HID * KCAT;
  if (j >= 0 && j < D_LAT * D_HID) W2b[j] = __float2bfloat16(W2[j] * sig[1]);
}

// ---------------- bf16 MFMA GEMM, 2-phase double-buffered LDS --------------
// C = tanh(A @ W^T + bias).
// OUT_MODE 0: bf16 -> Cb[m*N+n]                      (gemm1)
// OUT_MODE 1: f32 -> P0[m*N+n]                       (loop gemm2)
// OUT_MODE 2: P0=F0, P1=X1, P2=X2 (all =val), Cb=zc  (eval0 gemm2 + warm)
// OUT_MODE 3: P0=F1, P1=F2 (=val)                    (eval1 gemm2 + warm)
template <int BM, int BN, int K, int OUT_MODE>
__global__ __launch_bounds__(256) void gemm_mfma(
    const __hip_bfloat16* __restrict__ A, const __hip_bfloat16* __restrict__ W,
    const float* __restrict__ bias, float* __restrict__ P0,
    float* __restrict__ P1, float* __restrict__ P2,
    __hip_bfloat16* __restrict__ Cb, int N) {
  __shared__ __align__(16) u16 lds[2][(BM + BN) * 64];
  const int tid = threadIdx.x;
  const int lane = tid & 63;
  const int wid = tid >> 6;
  const int wy = wid >> 1, wx = wid & 1;
  constexpr int WM = BM / 2, WN = BN / 2;
  constexpr int MB = WM / 16, NB = WN / 16;
  constexpr int NK = K / 64;
  const int bm = blockIdx.x * BM;
  const int bn = blockIdx.y * BN;
  const int rlo = lane & 15, quad = lane >> 4;

  f32x4 acc[MB][NB] = {};

  auto stage = [&](u16* base, int k0) {
    u16* As = base;
    u16* Ws = base + BM * 64;
    for (int c = tid; c < BM * 8; c += 256) {
      int r = c >> 3, o = (c & 7) ^ (r & 7);
      __builtin_amdgcn_global_load_lds(
          (const __attribute__((address_space(1))) void*)(A + (size_t)(bm + r) * K + k0 + o * 8),
          (__attribute__((address_space(3))) void*)(As + c * 8), 16, 0, 0);
    }
    for (int c = tid; c < BN * 8; c += 256) {
      int r = c >> 3, o = (c & 7) ^ (r & 7);
      __builtin_amdgcn_global_load_lds(
          (const __attribute__((address_space(1))) void*)(W + (size_t)(bn + r) * K + k0 + o * 8),
          (__attribute__((address_space(3))) void*)(Ws + c * 8), 16, 0, 0);
    }
  };
  auto compute = [&](const u16* base) {
    const u16* As = base;
    const u16* Ws = base + BM * 64;
#pragma unroll
    for (int kk = 0; kk < 2; kk++) {
      bf16x8 af[MB], bfr[NB];
#pragma unroll
      for (int mb = 0; mb < MB; mb++) {
        int r = wy * WM + mb * 16 + rlo;
        int o = (kk * 4 + quad) ^ (r & 7);
        af[mb] = *(const bf16x8*)(As + (r * 8 + o) * 8);
      }
#pragma unroll
      for (int nb = 0; nb < NB; nb++) {
        int r = wx * WN + nb * 16 + rlo;
        int o = (kk * 4 + quad) ^ (r & 7);
        bfr[nb] = *(const bf16x8*)(Ws + (r * 8 + o) * 8);
      }
#pragma unroll
      for (int mb = 0; mb < MB; mb++)
#pragma unroll
        for (int nb = 0; nb < NB; nb++)
          acc[mb][nb] = __builtin_amdgcn_mfma_f32_16x16x32_bf16(
              af[mb], bfr[nb], acc[mb][nb], 0, 0, 0);
    }
  };

  stage(&lds[0][0], 0);
  __syncthreads();
#pragma unroll 2
  for (int step = 0; step < NK; step++) {
    u16* cur = (step & 1) ? &lds[1][0] : &lds[0][0];
    u16* nxt = (step & 1) ? &lds[0][0] : &lds[1][0];
    if (step + 1 < NK) stage(nxt, (step + 1) * 64);
    compute(cur);
    if (step + 1 < NK) __syncthreads();
  }

#pragma unroll
  for (int mb = 0; mb < MB; mb++) {
#pragma unroll
    for (int nb = 0; nb < NB; nb++) {
      int n = bn + wx * WN + nb * 16 + rlo;
      float bv = bias[n];
#pragma unroll
      for (int rg = 0; rg < 4; rg++) {
        int m = bm + wy * WM + mb * 16 + quad * 4 + rg;
        float val = tanhf(acc[mb][nb][rg] + bv);
        size_t idx = (size_t)m * N + n;
        if constexpr (OUT_MODE == 0) {
          Cb[idx] = __float2bfloat16(val);
        } else if constexpr (OUT_MODE == 1) {
          P0[idx] = val;
        } else if constexpr (OUT_MODE == 2) {
          P0[idx] = val;                      // F0
          P1[idx] = val;                      // X1 = F0
          P2[idx] = val;                      // X2 = F0
          Cb[(size_t)m * KCAT + n] = __float2bfloat16(val);  // zc left
        } else {
          P0[idx] = val;                      // F1
          P1[idx] = val;                      // F2 = F1
        }
      }
    }
  }
}

// ---------------- Anderson step v2.1 (wave per row, reg-resident, f32) -----
template <int MK>
__global__ __launch_bounds__(256) void anderson_step_kernel(
    const float* __restrict__ Xh, const float* __restrict__ Fh,
    float* __restrict__ Xw, __hip_bfloat16* __restrict__ zc, int t) {
  const int lane = threadIdx.x & 63;
  const int wid = threadIdx.x >> 6;
  const int b = blockIdx.x * 4 + wid;
  const int base = b * D_LAT + 4 * lane;

  f32x4 f[MK + 1], x[MK + 1];
#pragma unroll
  for (int i = 0; i <= MK; i++) {
    int sl = (t - 1 - i) % NRING;
    f[i] = *(const f32x4*)(Fh + (size_t)sl * SLOT + base);
    x[i] = *(const f32x4*)(Xh + (size_t)sl * SLOT + base);
  }

  const f32x4 r = f[0] - x[0];
  f32x4 dF[MK], dG[MK];
#pragma unroll
  for (int i = 0; i < MK; i++) {
    dF[i] = f[i] - f[i + 1];
    dG[i] = dF[i] - (x[i] - x[i + 1]);
  }

  constexpr int NV = MK * (MK + 1) / 2 + MK;
  float vals[NV];
  {
    int p = 0;
#pragma unroll
    for (int i = 0; i < MK; i++)
#pragma unroll
      for (int j = i; j < MK; j++) {
        f32x4 q = dG[i] * dG[j];
        vals[p++] = q[0] + q[1] + q[2] + q[3];
      }
#pragma unroll
    for (int i = 0; i < MK; i++) {
      f32x4 q = dG[i] * r;
      vals[p++] = q[0] + q[1] + q[2] + q[3];
    }
  }
#pragma unroll
  for (int off = 1; off <= 32; off <<= 1)
#pragma unroll
    for (int v = 0; v < NV; v++) vals[v] += __shfl_xor(vals[v], off, 64);

  float A[MK][MK], bv[MK], alpha[MK];
  {
    int p = 0;
#pragma unroll
    for (int i = 0; i < MK; i++)
#pragma unroll
      for (int j = i; j < MK; j++) {
        A[i][j] = vals[p];
        A[j][i] = vals[p];
        p++;
      }
#pragma unroll
    for (int i = 0; i < MK; i++) A[i][i] += 1e-4f;
#pragma unroll
    for (int i = 0; i < MK; i++) bv[i] = vals[p++];
  }

#pragma unroll
  for (int c = 0; c < MK; c++) {
    float inv = 1.0f / A[c][c];
#pragma unroll
    for (int rr = c + 1; rr < MK; rr++) {
      float fct = A[rr][c] * inv;
#pragma unroll
      for (int cc = c; cc < MK; cc++) A[rr][cc] -= fct * A[c][cc];
      bv[rr] -= fct * bv[c];
    }
  }
#pragma unroll
  for (int i = MK - 1; i >= 0; i--) {
    float s = bv[i];
#pragma unroll
    for (int j = i + 1; j < MK; j++) s -= A[i][j] * alpha[j];
    alpha[i] = s / A[i][i];
  }

  f32x4 xo = f[0];
#pragma unroll
  for (int i = 0; i < MK; i++) xo -= dF[i] * alpha[i];
  *(f32x4*)(Xw + base) = xo;
  if (zc != nullptr) {
    union { __hip_bfloat16 h[4]; unsigned long long u; } cv;
#pragma unroll
    for (int j = 0; j < 4; j++) cv.h[j] = __float2bfloat16(xo[j]);
    *(unsigned long long*)(zc + (size_t)b * KCAT + 4 * lane) = cv.u;
  }
}

// ---------------- host orchestration ---------------------------------------
extern "C" void kernel_launch(void* const* d_in, const int* in_sizes, int n_in,
                              void* d_out, int out_size, void* d_ws,
                              size_t ws_size, hipStream_t stream) {
  const float* ctx = (const float*)d_in[0];
  const float* W1 = (const float*)d_in[1];
  const float* b1 = (const float*)d_in[2];
  const float* W2 = (const float*)d_in[3];
  const float* b2 = (const float*)d_in[4];
  float* out = (float*)d_out;

  float* ws = (float*)d_ws;
  float* sig = ws;                       // 16
  float* vA = ws + 16;                   // 512
  float* vB = vA + KCAT;                 // 512
  float* uA = vB + KCAT;                 // 256
  float* uB = uA + D_LAT;                // 256
  float* G1p = uB + D_LAT;               // 512*512
  float* G2 = G1p + KCAT * KCAT;         // 256*256
  float* Xh = G2 + D_LAT * D_LAT;        // 7*SLOT
  float* Fh = Xh + NRING * SLOT;         // 7*SLOT
  __hip_bfloat16* W1b = (__hip_bfloat16*)(Fh + NRING * SLOT);  // 524288
  __hip_bfloat16* W2b = W1b + D_HID * KCAT;                    // 262144
  __hip_bfloat16* zc = W2b + D_LAT * D_HID;                    // 2048*512
  __hip_bfloat16* hb = zc + B_ROWS * KCAT;                     // 2048*1024
  // ~38.5 MB total

  init_kernel<<<(B_ROWS * KCAT + 255) / 256, 256, 0, stream>>>(
      ctx, zc, vA, uA, G1p, G2, Xh);
  // Gram (1024+256) + colsum (64)
  gram_kernel<<<1344, 256, 0, stream>>>(W1, W2, G1p, G2, vA);

  // damped power chain: u-side its 1..21 (u0=ones->u21); v-side its 2..21
  for (int it = 1; it <= 21; it++) {
    const float* vi; float* vo;
    const float* ui; float* uo;
    if (it & 1) { vi = vB; vo = vA; ui = uA; uo = uB; }
    else        { vi = vA; vo = vB; ui = uB; uo = uA; }
    pmv_kernel<<<192, 256, 0, stream>>>(G1p, G2, vi, vo, ui, uo, it >= 2);
  }
  // final: vA=v21, vB=v20, uA=u20, uB=u21
  sigma_kernel<<<1, 256, 0, stream>>>(vA, vB, uA, uB, sig);
  wfold_kernel<<<(D_HID * KCAT + D_LAT * D_HID + 255) / 256, 256, 0, stream>>>(
      W1, W2, sig, W1b, W2b);

  dim3 g1(B_ROWS / 64, D_HID / 64);
  dim3 g2(B_ROWS / 32, D_LAT / 32);

  // eval0: F0 = f(0|ctx); epilogue also writes X1=F0, X2=F0, zc=bf16(F0)
  gemm_mfma<64, 64, KCAT, 0><<<g1, 256, 0, stream>>>(
      zc, W1b, b1, nullptr, nullptr, nullptr, hb, D_HID);
  gemm_mfma<32, 32, D_HID, 2><<<g2, 256, 0, stream>>>(
      hb, W2b, b2, Fh, Xh + SLOT, Xh + 2 * SLOT, zc, D_LAT);
  // eval1: F1 = f(X1); epilogue also writes F2=F1
  gemm_mfma<64, 64, KCAT, 0><<<g1, 256, 0, stream>>>(
      zc, W1b, b1, nullptr, nullptr, nullptr, hb, D_HID);
  gemm_mfma<32, 32, D_HID, 3><<<g2, 256, 0, stream>>>(
      hb, W2b, b2, Fh + SLOT, Fh + 2 * SLOT, nullptr, nullptr, D_LAT);

  // Anderson loop: t = 3..25
  for (int t = 3; t <= 25; t++) {
    int mk = (t - 1 < 5) ? (t - 1) : 5;
    float* Xw = (t == 25) ? out : (Xh + (t % NRING) * SLOT);
    __hip_bfloat16* zarg = (t == 25) ? nullptr : zc;
    dim3 g(B_ROWS / 4);
    if (mk == 2)
      anderson_step_kernel<2><<<g, 256, 0, stream>>>(Xh, Fh, Xw, zarg, t);
    else if (mk == 3)
      anderson_step_kernel<3><<<g, 256, 0, stream>>>(Xh, Fh, Xw, zarg, t);
    else if (mk == 4)
      anderson_step_kernel<4><<<g, 256, 0, stream>>>(Xh, Fh, Xw, zarg, t);
    else
      anderson_step_kernel<5><<<g, 256, 0, stream>>>(Xh, Fh, Xw, zarg, t);
    if (t < 25) {
      gemm_mfma<64, 64, KCAT, 0><<<g1, 256, 0, stream>>>(
          zc, W1b, b1, nullptr, nullptr, nullptr, hb, D_HID);
      gemm_mfma<32, 32, D_HID, 1><<<g2, 256, 0, stream>>>(
          hb, W2b, b2, Fh + (t % NRING) * SLOT, nullptr, nullptr, nullptr,
          D_LAT);
    }
  }
}